// Round 2
// baseline (292.311 us; speedup 1.0000x reference)
//
#include <hip/hip_runtime.h>

// DCT_26688926778120: x (B=8,C=3,T=32,H=256,W=256) fp32
//   -> grayscale(0.2989,0.587,0.114) -> 8x8 blocks -> 2D DCT-II (norm=None)
//   out (B,T,1024,8,8) fp32.
// Memory-bound: 201 MB read + 67 MB write -> ~43 us floor at 6.3 TB/s.
//
// R2 structure: grid=2048 wgs, each handles 4 strips (strip = 8 pixel rows of
// one (b,t)). Double-buffered LDS + next-strip loads issued BEFORE the
// barrier, so HBM traffic stays in flight across every compute phase
// (de-convoys the R1 load->barrier->compute->exit lockstep).

#define TPB 256
#define GRID 2048
#define NSTRIP 8192   // B*T*(H/8)

// D[k][n] = 2*cos(pi*(2n+1)*k/16), correctly-rounded literals.
#define DCT_TABLE { \
  2.0f, 2.0f, 2.0f, 2.0f, 2.0f, 2.0f, 2.0f, 2.0f, \
  1.9615705608064609f, 1.6629392246050905f, 1.1111404660392044f, 0.3901806440322565f, \
 -0.3901806440322565f,-1.1111404660392044f,-1.6629392246050905f,-1.9615705608064609f, \
  1.8477590650225735f, 0.7653668647301796f,-0.7653668647301796f,-1.8477590650225735f, \
 -1.8477590650225735f,-0.7653668647301796f, 0.7653668647301796f, 1.8477590650225735f, \
  1.6629392246050905f,-0.3901806440322565f,-1.9615705608064609f,-1.1111404660392044f, \
  1.1111404660392044f, 1.9615705608064609f, 0.3901806440322565f,-1.6629392246050905f, \
  1.4142135623730951f,-1.4142135623730951f,-1.4142135623730951f, 1.4142135623730951f, \
  1.4142135623730951f,-1.4142135623730951f,-1.4142135623730951f, 1.4142135623730951f, \
  1.1111404660392044f,-1.9615705608064609f, 0.3901806440322565f, 1.6629392246050905f, \
 -1.6629392246050905f,-0.3901806440322565f, 1.9615705608064609f,-1.1111404660392044f, \
  0.7653668647301796f,-1.8477590650225735f, 1.8477590650225735f,-0.7653668647301796f, \
 -0.7653668647301796f, 1.8477590650225735f,-1.8477590650225735f, 0.7653668647301796f, \
  0.3901806440322565f,-1.1111404660392044f, 1.6629392246050905f,-1.9615705608064609f, \
  1.9615705608064609f,-1.6629392246050905f, 1.1111404660392044f,-0.3901806440322565f  \
}

// constexpr copy: stage-B uses compile-time indices -> folded to literals.
constexpr float DCT8C[64] = DCT_TABLE;
// __constant__ copy: lane-varying init of the LDS broadcast table for stage A.
__device__ __constant__ float DCT8G[64] = DCT_TABLE;

__global__ __launch_bounds__(TPB) void dct_gray_kernel(
    const float* __restrict__ x, float* __restrict__ out) {
  constexpr int T = 32, H = 256, W = 256;
  __shared__ float g[2][8][256];  // 16 KB double-buffered grayscale strip
  __shared__ float Dm[64];        // stage-A broadcast table

  const int tid = threadIdx.x;
  const int bid = blockIdx.x;
  if (tid < 64) Dm[tid] = DCT8G[tid];

  const size_t cstride = (size_t)T * H * W;  // channel stride (8 MB)
  const float w0 = 0.2989f, w1 = 0.587f, w2 = 0.114f;

  // per-thread load geometry (strip-invariant)
  const int r0 = tid >> 6;            // rows r0, r0+4
  const int c4 = tid & 63;            // float4 column
  const size_t lane_off0 = (size_t)r0 * W + (size_t)(c4 * 4);
  const size_t lane_off1 = (size_t)(r0 + 4) * W + (size_t)(c4 * 4);

  float4 a[2][3];  // [row-iter][channel] in-flight loads

  auto issue_loads = [&](int strip) {
    const int bt = strip >> 5, hb = strip & 31;
    const int b = bt >> 5, t = bt & 31;
    const size_t base0 =
        ((size_t)(b * 3) * T + (size_t)t) * (size_t)(H * W) +
        (size_t)hb * 8 * W;
    const float* p0 = x + base0 + lane_off0;
    const float* p1 = x + base0 + lane_off1;
    a[0][0] = *(const float4*)(p0);
    a[0][1] = *(const float4*)(p0 + cstride);
    a[0][2] = *(const float4*)(p0 + 2 * cstride);
    a[1][0] = *(const float4*)(p1);
    a[1][1] = *(const float4*)(p1 + cstride);
    a[1][2] = *(const float4*)(p1 + 2 * cstride);
  };

  issue_loads(bid);  // prologue: strip 0 of this wg

  int buf = 0;
  const int p = tid >> 3;   // block index within strip (0..31)
  const int k = tid & 7;    // output row within block

#pragma unroll
  for (int j = 0; j < 4; ++j) {
    const int s = bid + j * GRID;

    // grayscale fuse + LDS write (consumes a[][]; waits vmcnt here)
#pragma unroll
    for (int it = 0; it < 2; ++it) {
      float4 gg;
      gg.x = w0 * a[it][0].x + w1 * a[it][1].x + w2 * a[it][2].x;
      gg.y = w0 * a[it][0].y + w1 * a[it][1].y + w2 * a[it][2].y;
      gg.z = w0 * a[it][0].z + w1 * a[it][1].z + w2 * a[it][2].z;
      gg.w = w0 * a[it][0].w + w1 * a[it][1].w + w2 * a[it][2].w;
      *(float4*)(&g[buf][r0 + it * 4][c4 * 4]) = gg;
    }

    // issue next strip's loads BEFORE the barrier -> in flight across compute
    if (j < 3) issue_loads(bid + (j + 1) * GRID);

    __syncthreads();

    // stage A: temp[m] = sum_n D[k][n] * g[n][p*8+m]
    float temp[8];
#pragma unroll
    for (int m = 0; m < 8; ++m) temp[m] = 0.0f;
#pragma unroll
    for (int n = 0; n < 8; ++n) {
      const float dkn = Dm[k * 8 + n];
      const float4 g0 = *(const float4*)(&g[buf][n][p * 8]);
      const float4 g1 = *(const float4*)(&g[buf][n][p * 8 + 4]);
      temp[0] += dkn * g0.x; temp[1] += dkn * g0.y;
      temp[2] += dkn * g0.z; temp[3] += dkn * g0.w;
      temp[4] += dkn * g1.x; temp[5] += dkn * g1.y;
      temp[6] += dkn * g1.z; temp[7] += dkn * g1.w;
    }

    // stage B: res[l] = sum_m temp[m] * D[l][m]  (literal constants)
    float res[8];
#pragma unroll
    for (int l = 0; l < 8; ++l) {
      float acc = temp[0] * DCT8C[l * 8 + 0];
#pragma unroll
      for (int m = 1; m < 8; ++m) acc += temp[m] * DCT8C[l * 8 + m];
      res[l] = acc;
    }

    // contiguous 8 KB per (wg, strip); thread writes 32 B at tid*8
    float* o = out + (size_t)s * 2048 + (size_t)tid * 8;
    *(float4*)(o)     = make_float4(res[0], res[1], res[2], res[3]);
    *(float4*)(o + 4) = make_float4(res[4], res[5], res[6], res[7]);

    buf ^= 1;
    // NOTE: single barrier per iter is sufficient with double buffering:
    // writes to g[buf] recur only after an intervening barrier that every
    // reader of g[buf] must have passed.
  }
}

extern "C" void kernel_launch(void* const* d_in, const int* in_sizes, int n_in,
                              void* d_out, int out_size, void* d_ws, size_t ws_size,
                              hipStream_t stream) {
  const float* x = (const float*)d_in[0];
  float* out = (float*)d_out;
  dct_gray_kernel<<<GRID, TPB, 0, stream>>>(x, out);
}